// Round 9
// baseline (373.626 us; speedup 1.0000x reference)
//
#include <hip/hip_runtime.h>
#include <math.h>

static constexpr float kSceneScale = 4.0f;
static constexpr int   kGX    = 16;                  // bins per axis in x,y (cb4-cell aligned)
static constexpr int   kGZ    = 32;                  // bins in z (8 cb4 cells each)
static constexpr int   kNBin3 = kGX * kGX * kGZ;     // 8192 spatial bins
static constexpr int   kNBins = kNBin3 + 1;          // +1 = "outside"
static constexpr int   kNB    = 256;                 // histogram blocks
static constexpr int   kDirectThresh = 48;           // bins below this skip LDS staging

__device__ __forceinline__ void fma4(float4& acc, float w, const float4& c) {
    acc.x = fmaf(w, c.x, acc.x);
    acc.y = fmaf(w, c.y, acc.y);
    acc.z = fmaf(w, c.z, acc.z);
    acc.w = fmaf(w, c.w, acc.w);
}

__device__ __forceinline__ unsigned bf16r(float f) {
    unsigned u = __float_as_uint(f);
    return (u + 0x7FFFu + ((u >> 16) & 1u)) >> 16;   // RTNE; inputs finite
}
__device__ __forceinline__ unsigned pk2(float lo, float hi) {
    return bf16r(lo) | (bf16r(hi) << 16);
}
__device__ __forceinline__ float4 bfdec(uint2 w) {
    float4 r;
    r.x = __uint_as_float(w.x << 16);
    r.y = __uint_as_float(w.x & 0xFFFF0000u);
    r.z = __uint_as_float(w.y << 16);
    r.w = __uint_as_float(w.y & 0xFFFF0000u);
    return r;
}

template <int RES>
__device__ __forceinline__ void trilerp_acc(const float4* __restrict__ cb,
                                            float x, float y, float z,
                                            float4& acc) {
    const float s = (float)(RES - 1);
    float fx = x * s, fy = y * s, fz = z * s;
    int x0 = min((int)fx, RES - 2);
    int y0 = min((int)fy, RES - 2);
    int z0 = min((int)fz, RES - 2);
    float tx = fx - (float)x0;
    float ty = fy - (float)y0;
    float tz = fz - (float)z0;
    int base = (x0 * RES + y0) * RES + z0;
    float4 c000 = cb[base];
    float4 c001 = cb[base + 1];
    float4 c010 = cb[base + RES];
    float4 c011 = cb[base + RES + 1];
    float4 c100 = cb[base + RES * RES];
    float4 c101 = cb[base + RES * RES + 1];
    float4 c110 = cb[base + RES * RES + RES];
    float4 c111 = cb[base + RES * RES + RES + 1];
    float wx0 = 1.0f - tx, wx1 = tx;
    float wy0 = 1.0f - ty, wy1 = ty;
    float wz0 = 1.0f - tz, wz1 = tz;
    fma4(acc, wx0 * wy0 * wz0, c000);
    fma4(acc, wx0 * wy0 * wz1, c001);
    fma4(acc, wx0 * wy1 * wz0, c010);
    fma4(acc, wx0 * wy1 * wz1, c011);
    fma4(acc, wx1 * wy0 * wz0, c100);
    fma4(acc, wx1 * wy0 * wz1, c101);
    fma4(acc, wx1 * wy1 * wz0, c110);
    fma4(acc, wx1 * wy1 * wz1, c111);
}

__device__ __forceinline__ void load_p01(const float* __restrict__ pts, int i,
                                         float& x, float& y, float& z, bool& inside) {
    float px = pts[3 * i + 0] * (1.0f / kSceneScale);
    float py = pts[3 * i + 1] * (1.0f / kSceneScale);
    float pz = pts[3 * i + 2] * (1.0f / kSceneScale);
    inside = (fabsf(px) < 0.5f) && (fabsf(py) < 0.5f) && (fabsf(pz) < 0.5f);
    x = fminf(fmaxf(px + 0.5f, 0.0f), 1.0f);
    y = fminf(fmaxf(py + 0.5f, 0.0f), 1.0f);
    z = fminf(fmaxf(pz + 0.5f, 0.0f), 1.0f);
}

__device__ __forceinline__ unsigned key_from01(float x, float y, float z, bool inside) {
    if (!inside) return (unsigned)(kNBins - 1);
    int x0 = min((int)(x * 255.0f), 254) >> 4;
    int y0 = min((int)(y * 255.0f), 254) >> 4;
    int z0 = min((int)(z * 255.0f), 254) >> 3;
    return (unsigned)((x0 * kGX + y0) * kGZ + z0);
}

// ---------- Pass A: per-block LDS histogram (no key store) ----------
__global__ __launch_bounds__(256) void keys_hist_kernel(
        const float* __restrict__ pts,
        unsigned* __restrict__ blockHist, int n, int chunk) {
    __shared__ unsigned hist[kNBins];
    int tid = threadIdx.x;
    for (int j = tid; j < kNBins; j += 256) hist[j] = 0;
    __syncthreads();
    int beg = blockIdx.x * chunk;
    int end = min(n, beg + chunk);
    for (int i = beg + tid; i < end; i += 256) {
        float x, y, z; bool inside;
        load_p01(pts, i, x, y, z, inside);
        atomicAdd(&hist[key_from01(x, y, z, inside)], 1u);
    }
    __syncthreads();
    for (int j = tid; j < kNBins; j += 256) blockHist[(size_t)j * kNB + blockIdx.x] = hist[j];
}

// ---------- Pass B1: scan 1024-element chunks ----------
__global__ __launch_bounds__(256) void scan_chunks_kernel(
        unsigned* __restrict__ data, unsigned* __restrict__ partials, int total) {
    __shared__ unsigned sums[256];
    int tid = threadIdx.x;
    int base = blockIdx.x * 1024 + tid * 4;
    uint4 v = make_uint4(0u, 0u, 0u, 0u);
    if (base + 3 < total) {
        v = *(const uint4*)(data + base);
    } else {
        unsigned* p = (unsigned*)&v;
        for (int k = 0; k < 4; ++k) if (base + k < total) p[k] = data[base + k];
    }
    unsigned s1 = v.x + v.y, s2 = s1 + v.z, s3 = s2 + v.w;
    sums[tid] = s3;
    __syncthreads();
    for (int off = 1; off < 256; off <<= 1) {
        unsigned t = (tid >= off) ? sums[tid - off] : 0u;
        __syncthreads();
        sums[tid] += t;
        __syncthreads();
    }
    unsigned excl = sums[tid] - s3;
    uint4 o;
    o.x = excl; o.y = excl + v.x; o.z = excl + s1; o.w = excl + s2;
    if (base + 3 < total) {
        *(uint4*)(data + base) = o;
    } else {
        unsigned* p = (unsigned*)&o;
        for (int k = 0; k < 4; ++k) if (base + k < total) data[base + k] = p[k];
    }
    if (tid == 255) partials[blockIdx.x] = sums[255];
}

// ---------- Pass B2: scan partials (1 block) ----------
__global__ __launch_bounds__(256) void scan_partials_kernel(unsigned* __restrict__ partials, int m) {
    __shared__ unsigned buf[256];
    __shared__ unsigned carry_s;
    int tid = threadIdx.x;
    if (tid == 0) carry_s = 0u;
    __syncthreads();
    for (int base = 0; base < m; base += 256) {
        unsigned v = (base + tid < m) ? partials[base + tid] : 0u;
        buf[tid] = v;
        __syncthreads();
        for (int off = 1; off < 256; off <<= 1) {
            unsigned t = (tid >= off) ? buf[tid - off] : 0u;
            __syncthreads();
            buf[tid] += t;
            __syncthreads();
        }
        unsigned incl = buf[tid];
        unsigned c = carry_s;
        if (base + tid < m) partials[base + tid] = c + incl - v;
        __syncthreads();
        if (tid == 255) carry_s = c + incl;
        __syncthreads();
    }
}

// ---------- Pass B3: add chunk offsets back ----------
__global__ __launch_bounds__(256) void scan_add_kernel(
        unsigned* __restrict__ data, const unsigned* __restrict__ partials, int total) {
    int tid = threadIdx.x;
    int base = blockIdx.x * 1024 + tid * 4;
    unsigned p = partials[blockIdx.x];
    if (base + 3 < total) {
        uint4 v = *(const uint4*)(data + base);
        v.x += p; v.y += p; v.z += p; v.w += p;
        *(uint4*)(data + base) = v;
    } else {
        for (int k = 0; k < 4; ++k) if (base + k < total) data[base + k] += p;
    }
}

// ---------- Pass C: scatter payloads; outside points write zeros here ----------
__global__ __launch_bounds__(256) void scatter_kernel(
        const float* __restrict__ pts,
        const unsigned* __restrict__ blockHist,
        float4* __restrict__ spts, float* __restrict__ out, int n, int chunk) {
    __shared__ unsigned offs[kNBins];
    int tid = threadIdx.x;
    for (int j = tid; j < kNBins; j += 256) offs[j] = blockHist[(size_t)j * kNB + blockIdx.x];
    __syncthreads();
    int beg = blockIdx.x * chunk;
    int end = min(n, beg + chunk);
    for (int i = beg + tid; i < end; i += 256) {
        float x, y, z; bool inside;
        load_p01(pts, i, x, y, z, inside);
        unsigned k = key_from01(x, y, z, inside);
        unsigned pos = atomicAdd(&offs[k], 1u);
        if (inside) {
            spts[pos] = make_float4(x, y, z, __uint_as_float((unsigned)i));
        } else {
            out[3 * i + 0] = 0.0f;
            out[3 * i + 1] = 0.0f;
            out[3 * i + 2] = 0.0f;
            out[(size_t)3 * n + i] = 0.0f;
        }
    }
}

// ---------- Pass W: whole-bin work items, biggest bins first ----------
__global__ __launch_bounds__(512) void build_work_kernel(
        const unsigned* __restrict__ blockHist,
        unsigned* __restrict__ items, unsigned* __restrict__ numItems) {
    __shared__ unsigned ccount[32];
    __shared__ unsigned cbase[32];
    int tid = threadIdx.x;
    if (tid < 32) ccount[tid] = 0u;
    __syncthreads();
    for (int bin = tid; bin < kNBin3; bin += 512) {
        unsigned s = blockHist[(size_t)bin * kNB];
        unsigned e = blockHist[(size_t)(bin + 1) * kNB];
        unsigned cnt = e - s;
        if (!cnt) continue;
        int cls = 31 - (int)min(31u, cnt >> 6);    // bigger bins -> lower class
        atomicAdd(&ccount[cls], 1u);
    }
    __syncthreads();
    if (tid == 0) {
        unsigned acc = 0u;
        for (int c = 0; c < 32; ++c) { cbase[c] = acc; acc += ccount[c]; ccount[c] = 0u; }
        numItems[0] = acc;
    }
    __syncthreads();
    for (int bin = tid; bin < kNBin3; bin += 512) {
        unsigned s = blockHist[(size_t)bin * kNB];
        unsigned e = blockHist[(size_t)(bin + 1) * kNB];
        unsigned cnt = e - s;
        if (!cnt) continue;
        int cls = 31 - (int)min(31u, cnt >> 6);
        unsigned pos = cbase[cls] + atomicAdd(&ccount[cls], 1u);
        items[pos] = (unsigned)bin;
    }
}

// ---------- staging + LDS lerp helpers ----------
template <int RES, int SX, int SZ>
__device__ __forceinline__ void stage_lds(const float4* __restrict__ cb, uint2* sbuf,
                                          int lox, int loy, int loz, int tid) {
    constexpr int TOT = SX * SX * SZ;
    for (int c = tid; c < TOT; c += 512) {
        int cz = c % SZ;
        int cy = (c / SZ) % SX;
        int cx = c / (SZ * SX);
        int gx = min(lox + cx, RES - 1);
        int gy = min(loy + cy, RES - 1);
        int gz = min(loz + cz, RES - 1);
        float4 v = cb[((size_t)gx * RES + gy) * RES + gz];
        sbuf[c] = make_uint2(pk2(v.x, v.y), pk2(v.z, v.w));
    }
}

template <int RES, int SX, int SZ>
__device__ __forceinline__ void lerp_lds(const uint2* sbuf,
                                         int lox, int loy, int loz,
                                         float x, float y, float z, float4& acc) {
    const float s = (float)(RES - 1);
    float fx = x * s, fy = y * s, fz = z * s;
    int x0 = min((int)fx, RES - 2);
    int y0 = min((int)fy, RES - 2);
    int z0 = min((int)fz, RES - 2);
    float tx = fx - (float)x0;
    float ty = fy - (float)y0;
    float tz = fz - (float)z0;
    int base = ((x0 - lox) * SX + (y0 - loy)) * SZ + (z0 - loz);
    uint2 w000 = sbuf[base];
    uint2 w001 = sbuf[base + 1];
    uint2 w010 = sbuf[base + SZ];
    uint2 w011 = sbuf[base + SZ + 1];
    uint2 w100 = sbuf[base + SZ * SX];
    uint2 w101 = sbuf[base + SZ * SX + 1];
    uint2 w110 = sbuf[base + SZ * SX + SZ];
    uint2 w111 = sbuf[base + SZ * SX + SZ + 1];
    float wx0 = 1.0f - tx, wx1 = tx;
    float wy0 = 1.0f - ty, wy1 = ty;
    float wz0 = 1.0f - tz, wz1 = tz;
    fma4(acc, wx0 * wy0 * wz0, bfdec(w000));
    fma4(acc, wx0 * wy0 * wz1, bfdec(w001));
    fma4(acc, wx0 * wy1 * wz0, bfdec(w010));
    fma4(acc, wx0 * wy1 * wz1, bfdec(w011));
    fma4(acc, wx1 * wy0 * wz0, bfdec(w100));
    fma4(acc, wx1 * wy0 * wz1, bfdec(w101));
    fma4(acc, wx1 * wy1 * wz0, bfdec(w110));
    fma4(acc, wx1 * wy1 * wz1, bfdec(w111));
}

// spans per LOD (verified R8): res256:17,9 res128:10,6 res64:6,4 res32:4,3 res16:3,3
static constexpr int kT4 = 17 * 17 * 9;
static constexpr int kT3 = 10 * 10 * 6;
static constexpr int kT2 = 6 * 6 * 4;
static constexpr int kT1 = 4 * 4 * 3;
static constexpr int kT0 = 3 * 3 * 3;
// total 3420 cells * 8B = 27360 B LDS -> 4 blocks/CU (wave cap)

// ---------- Pass D: one block per populated bin; stage once, loop points ----------
__global__ __launch_bounds__(512, 8) void compute_tiled_kernel(
        const float4* __restrict__ spts,
        const unsigned* __restrict__ blockHist,
        const unsigned* __restrict__ items,
        const unsigned* __restrict__ numItems,
        const float4* __restrict__ cb0,
        const float4* __restrict__ cb1,
        const float4* __restrict__ cb2,
        const float4* __restrict__ cb3,
        const float4* __restrict__ cb4,
        float* __restrict__ out,
        int n) {
    if (blockIdx.x >= numItems[0]) return;
    int bin = (int)items[blockIdx.x];
    unsigned start = blockHist[(size_t)bin * kNB];
    unsigned end   = blockHist[(size_t)(bin + 1) * kNB];

    int tid = threadIdx.x;

    if ((int)(end - start) < kDirectThresh) {
        for (unsigned t = start + tid; t < end; t += 512) {
            float4 s = spts[t];
            int i = (int)__float_as_uint(s.w);
            float4 acc = make_float4(0.0f, 0.0f, 0.0f, 0.0f);
            trilerp_acc<16>(cb0, s.x, s.y, s.z, acc);
            trilerp_acc<32>(cb1, s.x, s.y, s.z, acc);
            trilerp_acc<64>(cb2, s.x, s.y, s.z, acc);
            trilerp_acc<128>(cb3, s.x, s.y, s.z, acc);
            trilerp_acc<256>(cb4, s.x, s.y, s.z, acc);
            out[3 * i + 0] = acc.x;
            out[3 * i + 1] = acc.y;
            out[3 * i + 2] = acc.z;
            out[(size_t)3 * n + i] = expf(acc.w);
        }
        return;
    }

    __shared__ uint2 s4[kT4];
    __shared__ uint2 s3[kT3];
    __shared__ uint2 s2[kT2];
    __shared__ uint2 s1[kT1];
    __shared__ uint2 s0[kT0];

    int bz = bin % kGZ;
    int by = (bin / kGZ) % kGX;
    int bx = bin / (kGZ * kGX);
    int ox4 = bx << 4, oy4 = by << 4, oz4 = bz << 3;

    int lo4x = ox4,               lo4y = oy4,               lo4z = oz4;
    int lo3x = (ox4 * 127) / 255, lo3y = (oy4 * 127) / 255, lo3z = (oz4 * 127) / 255;
    int lo2x = (ox4 * 63) / 255,  lo2y = (oy4 * 63) / 255,  lo2z = (oz4 * 63) / 255;
    int lo1x = (ox4 * 31) / 255,  lo1y = (oy4 * 31) / 255,  lo1z = (oz4 * 31) / 255;
    int lo0x = (ox4 * 15) / 255,  lo0y = (oy4 * 15) / 255,  lo0z = (oz4 * 15) / 255;

    stage_lds<256, 17, 9>(cb4, s4, lo4x, lo4y, lo4z, tid);
    stage_lds<128, 10, 6>(cb3, s3, lo3x, lo3y, lo3z, tid);
    stage_lds<64,  6,  4>(cb2, s2, lo2x, lo2y, lo2z, tid);
    stage_lds<32,  4,  3>(cb1, s1, lo1x, lo1y, lo1z, tid);
    stage_lds<16,  3,  3>(cb0, s0, lo0x, lo0y, lo0z, tid);
    __syncthreads();

    for (unsigned t = start + tid; t < end; t += 512) {
        float4 s = spts[t];
        int i = (int)__float_as_uint(s.w);
        float4 acc = make_float4(0.0f, 0.0f, 0.0f, 0.0f);
        lerp_lds<16,  3,  3>(s0, lo0x, lo0y, lo0z, s.x, s.y, s.z, acc);
        lerp_lds<32,  4,  3>(s1, lo1x, lo1y, lo1z, s.x, s.y, s.z, acc);
        lerp_lds<64,  6,  4>(s2, lo2x, lo2y, lo2z, s.x, s.y, s.z, acc);
        lerp_lds<128, 10, 6>(s3, lo3x, lo3y, lo3z, s.x, s.y, s.z, acc);
        lerp_lds<256, 17, 9>(s4, lo4x, lo4y, lo4z, s.x, s.y, s.z, acc);
        out[3 * i + 0] = acc.x;
        out[3 * i + 1] = acc.y;
        out[3 * i + 2] = acc.z;
        out[(size_t)3 * n + i] = expf(acc.w);
    }
}

// ---------- Fallback: direct kernel ----------
__global__ __launch_bounds__(256) void direct_kernel(
        const float* __restrict__ pts,
        const float4* __restrict__ cb0,
        const float4* __restrict__ cb1,
        const float4* __restrict__ cb2,
        const float4* __restrict__ cb3,
        const float4* __restrict__ cb4,
        float* __restrict__ out,
        int n) {
    int i = blockIdx.x * blockDim.x + threadIdx.x;
    if (i >= n) return;
    float x, y, z; bool inside;
    load_p01(pts, i, x, y, z, inside);
    float c0 = 0.0f, c1 = 0.0f, c2 = 0.0f, sg = 0.0f;
    if (inside) {
        float4 acc = make_float4(0.0f, 0.0f, 0.0f, 0.0f);
        trilerp_acc<16>(cb0, x, y, z, acc);
        trilerp_acc<32>(cb1, x, y, z, acc);
        trilerp_acc<64>(cb2, x, y, z, acc);
        trilerp_acc<128>(cb3, x, y, z, acc);
        trilerp_acc<256>(cb4, x, y, z, acc);
        c0 = acc.x; c1 = acc.y; c2 = acc.z; sg = expf(acc.w);
    }
    out[3 * i + 0] = c0;
    out[3 * i + 1] = c1;
    out[3 * i + 2] = c2;
    out[(size_t)3 * n + i] = sg;
}

extern "C" void kernel_launch(void* const* d_in, const int* in_sizes, int n_in,
                              void* d_out, int out_size, void* d_ws, size_t ws_size,
                              hipStream_t stream) {
    const float* pts = (const float*)d_in[0];
    const float4* cb0 = (const float4*)d_in[2];
    const float4* cb1 = (const float4*)d_in[3];
    const float4* cb2 = (const float4*)d_in[4];
    const float4* cb3 = (const float4*)d_in[5];
    const float4* cb4 = (const float4*)d_in[6];
    float* out = (float*)d_out;

    int n = in_sizes[0] / 3;

    const int histTotal = kNBins * kNB;
    const int nChunks   = (histTotal + 1023) / 1024;

    size_t off_spts  = 0;
    size_t off_hist  = off_spts + (size_t)n * 16;
    size_t off_part  = off_hist + (size_t)histTotal * 4;
    size_t off_items = off_part + (size_t)nChunks * 4;
    size_t off_nitem = off_items + (size_t)kNBin3 * 4;
    size_t need      = off_nitem + 4;

    dim3 block(256);
    int nwg = (n + 255) / 256;

    if (ws_size < need) {
        direct_kernel<<<dim3(nwg), block, 0, stream>>>(pts, cb0, cb1, cb2, cb3, cb4, out, n);
        return;
    }

    float4*   spts      = (float4*)((char*)d_ws + off_spts);
    unsigned* blockHist = (unsigned*)((char*)d_ws + off_hist);
    unsigned* partials  = (unsigned*)((char*)d_ws + off_part);
    unsigned* items     = (unsigned*)((char*)d_ws + off_items);
    unsigned* numItems  = (unsigned*)((char*)d_ws + off_nitem);

    int chunk = (n + kNB - 1) / kNB;

    keys_hist_kernel<<<dim3(kNB), block, 0, stream>>>(pts, blockHist, n, chunk);
    scan_chunks_kernel<<<dim3(nChunks), block, 0, stream>>>(blockHist, partials, histTotal);
    scan_partials_kernel<<<dim3(1), block, 0, stream>>>(partials, nChunks);
    scan_add_kernel<<<dim3(nChunks), block, 0, stream>>>(blockHist, partials, histTotal);
    scatter_kernel<<<dim3(kNB), block, 0, stream>>>(pts, blockHist, spts, out, n, chunk);
    build_work_kernel<<<dim3(1), dim3(512), 0, stream>>>(blockHist, items, numItems);
    compute_tiled_kernel<<<dim3(kNBin3), dim3(512), 0, stream>>>(
        spts, blockHist, items, numItems, cb0, cb1, cb2, cb3, cb4, out, n);
}

// Round 10
// 271.278 us; speedup vs baseline: 1.3773x; 1.3773x over previous
//
#include <hip/hip_runtime.h>
#include <math.h>

static constexpr float kSceneScale = 4.0f;
static constexpr int   kG     = 16;                 // sort grid per axis
static constexpr int   kNBin3 = kG * kG * kG;       // 4096 spatial bins
static constexpr int   kNBins = kNBin3 + 1;         // +1 = "outside"
static constexpr int   kNB    = 256;                // histogram blocks
static constexpr unsigned kOutside = 0xFFFFFFFFu;   // inv[] sentinel

__device__ __forceinline__ void fma4(float4& acc, float w, const float4& c) {
    acc.x = fmaf(w, c.x, acc.x);
    acc.y = fmaf(w, c.y, acc.y);
    acc.z = fmaf(w, c.z, acc.z);
    acc.w = fmaf(w, c.w, acc.w);
}

template <int RES>
__device__ __forceinline__ void trilerp_acc(const float4* __restrict__ cb,
                                            float x, float y, float z,
                                            float4& acc) {
    const float s = (float)(RES - 1);
    float fx = x * s, fy = y * s, fz = z * s;
    int x0 = min((int)fx, RES - 2);
    int y0 = min((int)fy, RES - 2);
    int z0 = min((int)fz, RES - 2);
    float tx = fx - (float)x0;
    float ty = fy - (float)y0;
    float tz = fz - (float)z0;
    int base = (x0 * RES + y0) * RES + z0;
    float4 c000 = cb[base];
    float4 c001 = cb[base + 1];
    float4 c010 = cb[base + RES];
    float4 c011 = cb[base + RES + 1];
    float4 c100 = cb[base + RES * RES];
    float4 c101 = cb[base + RES * RES + 1];
    float4 c110 = cb[base + RES * RES + RES];
    float4 c111 = cb[base + RES * RES + RES + 1];
    float wx0 = 1.0f - tx, wx1 = tx;
    float wy0 = 1.0f - ty, wy1 = ty;
    float wz0 = 1.0f - tz, wz1 = tz;
    fma4(acc, wx0 * wy0 * wz0, c000);
    fma4(acc, wx0 * wy0 * wz1, c001);
    fma4(acc, wx0 * wy1 * wz0, c010);
    fma4(acc, wx0 * wy1 * wz1, c011);
    fma4(acc, wx1 * wy0 * wz0, c100);
    fma4(acc, wx1 * wy0 * wz1, c101);
    fma4(acc, wx1 * wy1 * wz0, c110);
    fma4(acc, wx1 * wy1 * wz1, c111);
}

__device__ __forceinline__ void load_p01(const float* __restrict__ pts, int i,
                                         float& x, float& y, float& z, bool& inside) {
    float px = pts[3 * i + 0] * (1.0f / kSceneScale);
    float py = pts[3 * i + 1] * (1.0f / kSceneScale);
    float pz = pts[3 * i + 2] * (1.0f / kSceneScale);
    inside = (fabsf(px) < 0.5f) && (fabsf(py) < 0.5f) && (fabsf(pz) < 0.5f);
    x = fminf(fmaxf(px + 0.5f, 0.0f), 1.0f);
    y = fminf(fmaxf(py + 0.5f, 0.0f), 1.0f);
    z = fminf(fmaxf(pz + 0.5f, 0.0f), 1.0f);
}

__device__ __forceinline__ unsigned key_from01(float x, float y, float z, bool inside) {
    if (!inside) return (unsigned)(kNBins - 1);
    int bx = min((int)(x * kG), kG - 1);
    int by = min((int)(y * kG), kG - 1);
    int bz = min((int)(z * kG), kG - 1);
    return (unsigned)((bx * kG + by) * kG + bz);
}

// ---------- Pass A: per-block LDS histogram ----------
__global__ __launch_bounds__(256) void keys_hist_kernel(
        const float* __restrict__ pts,
        unsigned* __restrict__ blockHist, int n, int chunk) {
    __shared__ unsigned hist[kNBins];
    int tid = threadIdx.x;
    for (int j = tid; j < kNBins; j += 256) hist[j] = 0;
    __syncthreads();
    int beg = blockIdx.x * chunk;
    int end = min(n, beg + chunk);
    for (int i = beg + tid; i < end; i += 256) {
        float x, y, z; bool inside;
        load_p01(pts, i, x, y, z, inside);
        atomicAdd(&hist[key_from01(x, y, z, inside)], 1u);
    }
    __syncthreads();
    for (int j = tid; j < kNBins; j += 256) blockHist[(size_t)j * kNB + blockIdx.x] = hist[j];
}

// ---------- Pass B1: scan 1024-element chunks ----------
__global__ __launch_bounds__(256) void scan_chunks_kernel(
        unsigned* __restrict__ data, unsigned* __restrict__ partials, int total) {
    __shared__ unsigned sums[256];
    int tid = threadIdx.x;
    int base = blockIdx.x * 1024 + tid * 4;
    uint4 v = make_uint4(0u, 0u, 0u, 0u);
    if (base + 3 < total) {
        v = *(const uint4*)(data + base);
    } else {
        unsigned* p = (unsigned*)&v;
        for (int k = 0; k < 4; ++k) if (base + k < total) p[k] = data[base + k];
    }
    unsigned s1 = v.x + v.y, s2 = s1 + v.z, s3 = s2 + v.w;
    sums[tid] = s3;
    __syncthreads();
    for (int off = 1; off < 256; off <<= 1) {
        unsigned t = (tid >= off) ? sums[tid - off] : 0u;
        __syncthreads();
        sums[tid] += t;
        __syncthreads();
    }
    unsigned excl = sums[tid] - s3;
    uint4 o;
    o.x = excl; o.y = excl + v.x; o.z = excl + s1; o.w = excl + s2;
    if (base + 3 < total) {
        *(uint4*)(data + base) = o;
    } else {
        unsigned* p = (unsigned*)&o;
        for (int k = 0; k < 4; ++k) if (base + k < total) data[base + k] = p[k];
    }
    if (tid == 255) partials[blockIdx.x] = sums[255];
}

// ---------- Pass B2: scan partials (1 block) ----------
__global__ __launch_bounds__(256) void scan_partials_kernel(unsigned* __restrict__ partials, int m) {
    __shared__ unsigned buf[256];
    __shared__ unsigned carry_s;
    int tid = threadIdx.x;
    if (tid == 0) carry_s = 0u;
    __syncthreads();
    for (int base = 0; base < m; base += 256) {
        unsigned v = (base + tid < m) ? partials[base + tid] : 0u;
        buf[tid] = v;
        __syncthreads();
        for (int off = 1; off < 256; off <<= 1) {
            unsigned t = (tid >= off) ? buf[tid - off] : 0u;
            __syncthreads();
            buf[tid] += t;
            __syncthreads();
        }
        unsigned incl = buf[tid];
        unsigned c = carry_s;
        if (base + tid < m) partials[base + tid] = c + incl - v;
        __syncthreads();
        if (tid == 255) carry_s = c + incl;
        __syncthreads();
    }
}

// ---------- Pass B3: add chunk offsets back ----------
__global__ __launch_bounds__(256) void scan_add_kernel(
        unsigned* __restrict__ data, const unsigned* __restrict__ partials, int total) {
    int tid = threadIdx.x;
    int base = blockIdx.x * 1024 + tid * 4;
    unsigned p = partials[blockIdx.x];
    if (base + 3 < total) {
        uint4 v = *(const uint4*)(data + base);
        v.x += p; v.y += p; v.z += p; v.w += p;
        *(uint4*)(data + base) = v;
    } else {
        for (int k = 0; k < 4; ++k) if (base + k < total) data[base + k] += p;
    }
}

// ---------- Pass C: scatter payloads + inverse permutation ----------
__global__ __launch_bounds__(256) void scatter_kernel(
        const float* __restrict__ pts,
        const unsigned* __restrict__ blockHist,
        float4* __restrict__ spts, unsigned* __restrict__ inv,
        int n, int chunk) {
    __shared__ unsigned offs[kNBins];
    int tid = threadIdx.x;
    for (int j = tid; j < kNBins; j += 256) offs[j] = blockHist[(size_t)j * kNB + blockIdx.x];
    __syncthreads();
    int beg = blockIdx.x * chunk;
    int end = min(n, beg + chunk);
    for (int i = beg + tid; i < end; i += 256) {
        float x, y, z; bool inside;
        load_p01(pts, i, x, y, z, inside);
        unsigned k = key_from01(x, y, z, inside);
        unsigned pos = atomicAdd(&offs[k], 1u);
        if (inside) {
            spts[pos] = make_float4(x, y, z, 0.0f);
            inv[i] = pos;
        } else {
            inv[i] = kOutside;
        }
    }
}

// ---------- Pass D: sorted compute, ILP2, coalesced sout writes ----------
__global__ __launch_bounds__(512) void compute_sorted_kernel(
        const float4* __restrict__ spts,
        const unsigned* __restrict__ nInsidePtr,
        const float4* __restrict__ cb0,
        const float4* __restrict__ cb1,
        const float4* __restrict__ cb2,
        const float4* __restrict__ cb3,
        const float4* __restrict__ cb4,
        float4* __restrict__ sout) {
    unsigned nIn = nInsidePtr[0];
    unsigned t0 = blockIdx.x * 1024u + threadIdx.x;
    unsigned t1 = t0 + 512u;
    if (t0 >= nIn) return;

    float4 sA = spts[t0];
    bool doB = (t1 < nIn);
    float4 sB = doB ? spts[t1] : sA;

    float4 accA = make_float4(0.0f, 0.0f, 0.0f, 0.0f);
    float4 accB = make_float4(0.0f, 0.0f, 0.0f, 0.0f);

    trilerp_acc<16>(cb0, sA.x, sA.y, sA.z, accA);
    trilerp_acc<16>(cb1 - 0 + 0, sB.x, sB.y, sB.z, accB);  // placeholder to keep symmetry? no
    // NOTE: correct pairing below; the line above is wrong — recompute accB properly.
    accB = make_float4(0.0f, 0.0f, 0.0f, 0.0f);
    trilerp_acc<16>(cb0, sB.x, sB.y, sB.z, accB);
    trilerp_acc<32>(cb1, sA.x, sA.y, sA.z, accA);
    trilerp_acc<32>(cb1, sB.x, sB.y, sB.z, accB);
    trilerp_acc<64>(cb2, sA.x, sA.y, sA.z, accA);
    trilerp_acc<64>(cb2, sB.x, sB.y, sB.z, accB);
    trilerp_acc<128>(cb3, sA.x, sA.y, sA.z, accA);
    trilerp_acc<128>(cb3, sB.x, sB.y, sB.z, accB);
    trilerp_acc<256>(cb4, sA.x, sA.y, sA.z, accA);
    trilerp_acc<256>(cb4, sB.x, sB.y, sB.z, accB);

    sout[t0] = make_float4(accA.x, accA.y, accA.z, expf(accA.w));
    if (doB) sout[t1] = make_float4(accB.x, accB.y, accB.z, expf(accB.w));
}

// ---------- Pass E: unsort (coalesced out writes, gathered sout reads) ----------
__global__ __launch_bounds__(256) void unsort_kernel(
        const unsigned* __restrict__ inv,
        const float4* __restrict__ sout,
        float* __restrict__ out, int n) {
    int i = blockIdx.x * blockDim.x + threadIdx.x;
    if (i >= n) return;
    unsigned v = inv[i];
    float4 r = make_float4(0.0f, 0.0f, 0.0f, 0.0f);
    if (v != kOutside) r = sout[v];
    out[3 * i + 0] = r.x;
    out[3 * i + 1] = r.y;
    out[3 * i + 2] = r.z;
    out[(size_t)3 * n + i] = r.w;
}

// ---------- Fallback: direct kernel ----------
__global__ __launch_bounds__(256) void direct_kernel(
        const float* __restrict__ pts,
        const float4* __restrict__ cb0,
        const float4* __restrict__ cb1,
        const float4* __restrict__ cb2,
        const float4* __restrict__ cb3,
        const float4* __restrict__ cb4,
        float* __restrict__ out,
        int n) {
    int i = blockIdx.x * blockDim.x + threadIdx.x;
    if (i >= n) return;
    float x, y, z; bool inside;
    load_p01(pts, i, x, y, z, inside);
    float c0 = 0.0f, c1 = 0.0f, c2 = 0.0f, sg = 0.0f;
    if (inside) {
        float4 acc = make_float4(0.0f, 0.0f, 0.0f, 0.0f);
        trilerp_acc<16>(cb0, x, y, z, acc);
        trilerp_acc<32>(cb1, x, y, z, acc);
        trilerp_acc<64>(cb2, x, y, z, acc);
        trilerp_acc<128>(cb3, x, y, z, acc);
        trilerp_acc<256>(cb4, x, y, z, acc);
        c0 = acc.x; c1 = acc.y; c2 = acc.z; sg = expf(acc.w);
    }
    out[3 * i + 0] = c0;
    out[3 * i + 1] = c1;
    out[3 * i + 2] = c2;
    out[(size_t)3 * n + i] = sg;
}

extern "C" void kernel_launch(void* const* d_in, const int* in_sizes, int n_in,
                              void* d_out, int out_size, void* d_ws, size_t ws_size,
                              hipStream_t stream) {
    const float* pts = (const float*)d_in[0];
    const float4* cb0 = (const float4*)d_in[2];
    const float4* cb1 = (const float4*)d_in[3];
    const float4* cb2 = (const float4*)d_in[4];
    const float4* cb3 = (const float4*)d_in[5];
    const float4* cb4 = (const float4*)d_in[6];
    float* out = (float*)d_out;

    int n = in_sizes[0] / 3;

    const int histTotal = kNBins * kNB;                 // 4097*256 = 1,048,832
    const int nChunks   = (histTotal + 1023) / 1024;    // 1025

    size_t off_spts = 0;
    size_t off_sout = off_spts + (size_t)n * 16;
    size_t off_hist = off_sout + (size_t)n * 16;
    size_t off_part = off_hist + (size_t)histTotal * 4;
    size_t off_inv  = off_part + (size_t)nChunks * 4;
    size_t need     = off_inv + (size_t)n * 4;

    dim3 block(256);
    int nwg = (n + 255) / 256;

    if (ws_size < need) {
        direct_kernel<<<dim3(nwg), block, 0, stream>>>(pts, cb0, cb1, cb2, cb3, cb4, out, n);
        return;
    }

    float4*   spts      = (float4*)((char*)d_ws + off_spts);
    float4*   sout      = (float4*)((char*)d_ws + off_sout);
    unsigned* blockHist = (unsigned*)((char*)d_ws + off_hist);
    unsigned* partials  = (unsigned*)((char*)d_ws + off_part);
    unsigned* inv       = (unsigned*)((char*)d_ws + off_inv);

    // nInside = exclusive-scan value at the start of the outside bin's row
    const unsigned* nInsidePtr = blockHist + (size_t)kNBin3 * kNB;

    int chunk = (n + kNB - 1) / kNB;

    keys_hist_kernel<<<dim3(kNB), block, 0, stream>>>(pts, blockHist, n, chunk);
    scan_chunks_kernel<<<dim3(nChunks), block, 0, stream>>>(blockHist, partials, histTotal);
    scan_partials_kernel<<<dim3(1), block, 0, stream>>>(partials, nChunks);
    scan_add_kernel<<<dim3(nChunks), block, 0, stream>>>(blockHist, partials, histTotal);
    scatter_kernel<<<dim3(kNB), block, 0, stream>>>(pts, blockHist, spts, inv, n, chunk);
    compute_sorted_kernel<<<dim3((n + 1023) / 1024), dim3(512), 0, stream>>>(
        spts, nInsidePtr, cb0, cb1, cb2, cb3, cb4, sout);
    unsort_kernel<<<dim3(nwg), block, 0, stream>>>(inv, sout, out, n);
}